// Round 9
// baseline (358.120 us; speedup 1.0000x reference)
//
#include <hip/hip_runtime.h>
#include <math.h>

#define MM 512
#define KK 100000
#define NB1 1024               // pass1/pass2 blocks (4 waves each -> 4096 waves)
#define NW  (NB1 * 4)          // total waves in pass kernels
#define NOUT 16                // k_out blocks

// ws float layout:
// [0..512)      v = W^T a1
// [512..1024)   u = W^T a2
// [1024..1536)  acc (k_out accumulator)        -- zeroed
// [1536]        Z                              -- zeroed
// [1537]        cnt (int)                      -- zeroed
// [2048..3072)  sumUp per-block sum x.u  [1024]
// [3072..4096)  zpart per-block Z        [1024]
// [16384..+KK)  s    (s_i = x_i . v)
// [131072..)    part[1024][512] colsum partials (2 MB)
//
// NOTE: no softmax max — e = relu(s+c) >= 0 and e_max ~ 6, so exp(e) <= ~1e3,
// Z <= ~1e7: comfortably fp32-safe; softmax is shift-invariant (identical math).

__device__ inline float waveSum(float v){
  #pragma unroll
  for(int off = 32; off > 0; off >>= 1) v += __shfl_down(v, off, 64);
  return v;   // total in lane 0
}
__device__ inline float dot8(float4 x0, float4 x1, float4 v0, float4 v1){
  return x0.x*v0.x + x0.y*v0.y + x0.z*v0.z + x0.w*v0.w
       + x1.x*v1.x + x1.y*v1.y + x1.z*v1.z + x1.w*v1.w;
}

// v,u = W^T a1, W^T a2 — non-atomic, LDS-reduced. 8 blocks x 512.
__global__ __launch_bounds__(512) void k_vu(const float* __restrict__ W,
                                            const float* __restrict__ a,
                                            float* __restrict__ v,
                                            float* __restrict__ u){
  __shared__ float lw[1024];
  int jl = threadIdx.x & 63, kg = threadIdx.x >> 6;
  int j  = blockIdx.x * 64 + jl;
  float pv = 0.f, pu = 0.f;
  for(int k = kg * 64; k < kg * 64 + 64; k++){
    float w = W[(size_t)k * MM + j];
    pv += w * a[k];
    pu += w * a[MM + k];
  }
  lw[kg * 64 + jl]       = pv;
  lw[512 + kg * 64 + jl] = pu;
  __syncthreads();
  if(threadIdx.x < 64){
    float sv = 0.f, su = 0.f;
    #pragma unroll
    for(int g = 0; g < 8; g++){
      sv += lw[g * 64 + threadIdx.x];
      su += lw[512 + g * 64 + threadIdx.x];
    }
    v[blockIdx.x * 64 + threadIdx.x] = sv;
    u[blockIdx.x * 64 + threadIdx.x] = su;
  }
}

// Pass 1: s_i = x_i.v (8-row batched butterfly reduce), sumU partials.
__global__ __launch_bounds__(256) void k_pass1(const float* __restrict__ x,
                                               const float* __restrict__ vv,
                                               const float* __restrict__ uu,
                                               float* __restrict__ s,
                                               float* __restrict__ sumUp){
  __shared__ float red[4];
  int tid  = threadIdx.x;
  int lane = tid & 63;
  int wid  = tid >> 6;
  int gw   = blockIdx.x * 4 + wid;

  const float4* v4 = (const float4*)vv;
  const float4* u4 = (const float4*)uu;
  float4 v0 = v4[lane], v1 = v4[64 + lane];
  float4 u0 = u4[lane], u1 = u4[64 + lane];
  float accU = 0.f;

  int myN = (KK - 1 - gw) / NW + 1;   // rows this wave owns (24 or 25)
  int k = 0;
  for(; k + 8 <= myN; k += 8){
    float d[8];
    #pragma unroll
    for(int r = 0; r < 8; r++){
      size_t row = (size_t)gw + (size_t)(k + r) * NW;
      const float4* xr = (const float4*)(x + row * MM);
      float4 x0 = xr[lane];
      float4 x1 = xr[64 + lane];
      d[r]  = dot8(x0, x1, v0, v1);
      accU += dot8(x0, x1, u0, u1);
    }
    // 8 independent butterfly chains
    #pragma unroll
    for(int off = 1; off < 64; off <<= 1){
      #pragma unroll
      for(int r = 0; r < 8; r++) d[r] += __shfl_xor(d[r], off, 64);
    }
    // lane l (l<8) selects d[l] and stores s[row_l]
    float s0 = (lane & 1) ? d[1] : d[0];
    float s1 = (lane & 1) ? d[3] : d[2];
    float s2 = (lane & 1) ? d[5] : d[4];
    float s3 = (lane & 1) ? d[7] : d[6];
    float t0 = (lane & 2) ? s1 : s0;
    float t1 = (lane & 2) ? s3 : s2;
    float rr = (lane & 4) ? t1 : t0;
    if(lane < 8) s[(size_t)gw + (size_t)(k + lane) * NW] = rr;
  }
  for(; k < myN; k++){
    size_t row = (size_t)gw + (size_t)k * NW;
    const float4* xr = (const float4*)(x + row * MM);
    float4 x0 = xr[lane];
    float4 x1 = xr[64 + lane];
    float d = dot8(x0, x1, v0, v1);
    accU += dot8(x0, x1, u0, u1);
    #pragma unroll
    for(int off = 1; off < 64; off <<= 1) d += __shfl_xor(d, off, 64);
    if(lane == 0) s[row] = d;
  }

  float ws_ = waveSum(accU);
  if(lane == 0) red[wid] = ws_;
  __syncthreads();
  if(tid == 0) sumUp[blockIdx.x] = red[0] + red[1] + red[2] + red[3];
}

// Pass 2: each block computes c itself; w_i = exp(relu(s_i+c)); per-block
// colsums -> part (non-atomic); per-block Z -> zpart (non-atomic).
__global__ __launch_bounds__(256) void k_pass2(const float* __restrict__ x,
                                               const float* __restrict__ s,
                                               const float* __restrict__ b,
                                               const float* __restrict__ a,
                                               const float* __restrict__ sumUp,
                                               float* __restrict__ part,
                                               float* __restrict__ zpart){
  __shared__ float red[4];
  __shared__ float lw[2048];   // 4 waves x 64 lanes x 8 cols
  int tid  = threadIdx.x;
  int lane = tid & 63;
  int wid  = tid >> 6;
  int gw   = blockIdx.x * 4 + wid;

  // ---- prologue: c = b.(a1+a2) + (sum_i x_i.u)/K ----
  float cv = b[tid]       * (a[tid]       + a[MM + tid])
           + b[tid + 256] * (a[tid + 256] + a[MM + tid + 256])
           + (sumUp[tid] + sumUp[tid + 256] + sumUp[tid + 512] + sumUp[tid + 768])
             * (1.0f / (float)KK);
  float csum = waveSum(cv);
  if(lane == 0) red[wid] = csum;
  __syncthreads();
  float c = red[0] + red[1] + red[2] + red[3];

  // ---- main streaming loop (8-row batched), m == 0 ----
  float4 a0 = make_float4(0,0,0,0), a1 = make_float4(0,0,0,0);
  float accZ = 0.f;
  int myN = (KK - 1 - gw) / NW + 1;
  int k = 0;
  for(; k + 8 <= myN; k += 8){
    float w[8];
    #pragma unroll
    for(int r = 0; r < 8; r++)
      w[r] = s[(size_t)gw + (size_t)(k + r) * NW];
    #pragma unroll
    for(int r = 0; r < 8; r++){
      w[r] = __expf(fmaxf(w[r] + c, 0.f));
      accZ += w[r];
    }
    #pragma unroll
    for(int r = 0; r < 8; r++){
      size_t row = (size_t)gw + (size_t)(k + r) * NW;
      const float4* xr = (const float4*)(x + row * MM);
      float4 x0 = xr[lane];
      float4 x1 = xr[64 + lane];
      a0.x += w[r] * x0.x; a0.y += w[r] * x0.y; a0.z += w[r] * x0.z; a0.w += w[r] * x0.w;
      a1.x += w[r] * x1.x; a1.y += w[r] * x1.y; a1.z += w[r] * x1.z; a1.w += w[r] * x1.w;
    }
  }
  for(; k < myN; k++){
    size_t row = (size_t)gw + (size_t)k * NW;
    float w = __expf(fmaxf(s[row] + c, 0.f));
    accZ += w;
    const float4* xr = (const float4*)(x + row * MM);
    float4 x0 = xr[lane];
    float4 x1 = xr[64 + lane];
    a0.x += w * x0.x; a0.y += w * x0.y; a0.z += w * x0.z; a0.w += w * x0.w;
    a1.x += w * x1.x; a1.y += w * x1.y; a1.z += w * x1.z; a1.w += w * x1.w;
  }

  // ---- tail: cross-wave sum via plain LDS, coalesced non-atomic output ----
  float zw = waveSum(accZ);
  __syncthreads();                 // prologue reads of red complete everywhere
  float4* lw4 = (float4*)lw;
  lw4[wid * 128 + lane * 2]     = a0;   // lane l: cols 4l+q     at w*512+l*8+q
  lw4[wid * 128 + lane * 2 + 1] = a1;   // cols 256+4l+q at w*512+l*8+4+q
  if(lane == 0) red[wid] = zw;
  __syncthreads();
  int l = tid >> 2, q = tid & 3;
  float s0 = lw[0*512 + l*8 + q]     + lw[1*512 + l*8 + q]
           + lw[2*512 + l*8 + q]     + lw[3*512 + l*8 + q];
  float s1 = lw[0*512 + l*8 + 4 + q] + lw[1*512 + l*8 + 4 + q]
           + lw[2*512 + l*8 + 4 + q] + lw[3*512 + l*8 + 4 + q];
  part[(size_t)blockIdx.x * 512 + tid]       = s0;
  part[(size_t)blockIdx.x * 512 + 256 + tid] = s1;
  if(tid == 0)
    zpart[blockIdx.x] = (red[0] + red[1] + red[2] + red[3]) * (1.0f / 64.0f);
}

// Reduce part[1024][512] + zpart[1024]; last block writes out = acc/Z.
__global__ __launch_bounds__(256) void k_out(const float* __restrict__ part,
                                             const float* __restrict__ zpart,
                                             float* __restrict__ acc,
                                             float* __restrict__ Zws,
                                             int* __restrict__ cnt,
                                             float* __restrict__ out){
  __shared__ int lastf;
  int tid = threadIdx.x;
  const float* p = part + (size_t)blockIdx.x * (NB1 / NOUT) * 512;
  float s0 = 0.f, s1 = 0.f;
  #pragma unroll 8
  for(int r = 0; r < NB1 / NOUT; r++){
    s0 += p[r * 512 + tid];
    s1 += p[r * 512 + 256 + tid];
  }
  float zz = (tid < NB1 / NOUT) ? zpart[blockIdx.x * (NB1 / NOUT) + tid] : 0.f;
  zz = waveSum(zz);   // wave 0 holds the full 64-entry sum in lane 0
  atomicAdd(&acc[tid],       s0);
  atomicAdd(&acc[tid + 256], s1);
  if(tid == 0) atomicAdd(Zws, zz);
  __threadfence();
  if(tid == 0) lastf = (atomicAdd(cnt, 1) == NOUT - 1) ? 1 : 0;
  __syncthreads();
  if(lastf){
    float z  = atomicAdd(Zws, 0.0f);                // coherent reads
    float v0 = atomicAdd(&acc[tid],       0.0f);
    float v1 = atomicAdd(&acc[tid + 256], 0.0f);
    out[tid]       = v0 / z;
    out[tid + 256] = v1 / z;
  }
}

extern "C" void kernel_launch(void* const* d_in, const int* in_sizes, int n_in,
                              void* d_out, int out_size, void* d_ws, size_t ws_size,
                              hipStream_t stream) {
  const float* x = (const float*)d_in[0];
  const float* W = (const float*)d_in[1];
  const float* b = (const float*)d_in[2];
  const float* a = (const float*)d_in[3];
  float* ws  = (float*)d_ws;
  float* out = (float*)d_out;

  float* v     = ws;
  float* u     = ws + 512;
  float* acc   = ws + 1024;
  float* Zws   = ws + 1536;
  int*   cnt   = (int*)(ws + 1537);
  float* sumUp = ws + 2048;
  float* zpart = ws + 3072;
  float* s     = ws + 16384;
  float* part  = ws + 131072;

  // zero acc, Z, cnt only
  hipMemsetAsync(ws + 1024, 0, 514 * sizeof(float), stream);

  k_vu   <<<8,    512, 0, stream>>>(W, a, v, u);
  k_pass1<<<NB1,  256, 0, stream>>>(x, v, u, s, sumUp);
  k_pass2<<<NB1,  256, 0, stream>>>(x, s, b, a, sumUp, part, zpart);
  k_out  <<<NOUT, 256, 0, stream>>>(part, zpart, acc, Zws, cnt, out);
}